// Round 10
// baseline (313.936 us; speedup 1.0000x reference)
//
#include <hip/hip_runtime.h>

#define D 128

typedef __attribute__((ext_vector_type(8))) short short8;
typedef __attribute__((ext_vector_type(4))) float f32x4;
typedef __attribute__((ext_vector_type(4))) int int4v;
typedef __attribute__((ext_vector_type(4))) unsigned int uint4v;
typedef __attribute__((ext_vector_type(4))) unsigned short ushort4v;

// fp32 -> bf16 bits, round-to-nearest-even
__device__ inline unsigned int f2bf_bits(float f) {
    unsigned int u = __float_as_uint(f);
    return (u + 0x7FFFu + ((u >> 16) & 1u)) >> 16;
}

__device__ inline float bfhi(unsigned int u) { return __uint_as_float(u << 16); }
__device__ inline float bflo(unsigned int u) { return __uint_as_float(u & 0xffff0000u); }

// ---------------- fused prep: x -> SLICED bf16 hi/lo [4][N][32], weight pack, zeroing ----
__global__ __launch_bounds__(256) void prep_kernel(
    const float* __restrict__ x,
    const float* __restrict__ W1l, const float* __restrict__ W1r,
    const float* __restrict__ W2l, const float* __restrict__ W2r,
    unsigned short* __restrict__ xsl_hi, unsigned short* __restrict__ xsl_lo,
    unsigned short* __restrict__ h1, unsigned short* __restrict__ l1,
    unsigned short* __restrict__ h2, unsigned short* __restrict__ l2,
    int n4, int ncast, int N, int* __restrict__ chist, int* __restrict__ csrpad)
{
    const int b = blockIdx.x;
    const int t = threadIdx.x;
    if (b < ncast) {
        int i = b * 256 + t;
        if (i >= n4) return;
        f32x4 v = *(const f32x4*)(x + (size_t)i * 4);
        ushort4v oh, ol;
        {
            unsigned int h; float hf;
            h = f2bf_bits(v.x); hf = __uint_as_float(h << 16);
            oh.x = (unsigned short)h; ol.x = (unsigned short)f2bf_bits(v.x - hf);
            h = f2bf_bits(v.y); hf = __uint_as_float(h << 16);
            oh.y = (unsigned short)h; ol.y = (unsigned short)f2bf_bits(v.y - hf);
            h = f2bf_bits(v.z); hf = __uint_as_float(h << 16);
            oh.z = (unsigned short)h; ol.z = (unsigned short)f2bf_bits(v.z - hf);
            h = f2bf_bits(v.w); hf = __uint_as_float(h << 16);
            oh.w = (unsigned short)h; ol.w = (unsigned short)f2bf_bits(v.w - hf);
        }
        // sliced layout: channel c of node -> [c>>5][node][c&31]; nt stores (write-once)
        int node = i >> 5;            // 32 4-float chunks per node
        int c0 = (i & 31) * 4;
        size_t o = (size_t)(c0 >> 5) * N * 32 + (size_t)node * 32 + (c0 & 31);
        __builtin_nontemporal_store(oh, (ushort4v*)(xsl_hi + o));
        __builtin_nontemporal_store(ol, (ushort4v*)(xsl_lo + o));
    } else if (b < ncast + 256) {
        // weight pack: B-frag order + bf16 hi/lo split (unchanged)
        int gidx = (b - ncast) * 256 + t;   // 0..65535
        int sel = gidx >> 15;
        int idx = gidx & 32767;
        int tt = idx >> 12;
        int ks = (idx >> 9) & 7;
        int lane = (idx >> 3) & 63;
        int j = idx & 7;
        int qq = lane >> 4, r16 = lane & 15;
        int k = ks * 32 + qq * 8 + j;
        int c = tt * 16 + r16;
        const float* Wl = sel ? W2l : W1l;
        const float* Wr = sel ? W2r : W1r;
        float v = (k < 128) ? Wl[k * 128 + c] : Wr[(k - 128) * 128 + c];
        unsigned int h = f2bf_bits(v);
        float hf = __uint_as_float(h << 16);
        unsigned int l = f2bf_bits(v - hf);
        (sel ? h2 : h1)[idx] = (unsigned short)h;
        (sel ? l2 : l1)[idx] = (unsigned short)l;
    } else {
        chist[t] = 0;
        if (t < 32) csrpad[t] = 0;
    }
}

// ---------------- pass A: coarse histogram (bucket = dst>>8) via LDS ----------------
__global__ __launch_bounds__(256) void coarse_count_kernel(const int* __restrict__ dst,
                                                           int* __restrict__ chist, int E) {
    __shared__ int h[256];
    h[threadIdx.x] = 0;
    __syncthreads();
    const int stride = gridDim.x * 256;
    for (int e = blockIdx.x * 256 + threadIdx.x; e < E; e += stride)
        atomicAdd(&h[dst[e] >> 8], 1);
    __syncthreads();
    int v = h[threadIdx.x];
    if (v) atomicAdd(&chist[threadIdx.x], v);
}

// ---------------- pass B: scan 256 bucket counts -> cbase (excl, 257) + gcur ----------------
__global__ __launch_bounds__(256) void scan256_kernel(const int* __restrict__ chist,
                                                      int* __restrict__ cbase,
                                                      int* __restrict__ gcur) {
    __shared__ int wsum[4];
    const int t = threadIdx.x, lane = t & 63, wv = t >> 6;
    int v = chist[t];
    int s = v;
#pragma unroll
    for (int o = 1; o < 64; o <<= 1) {
        int u = __shfl_up(s, o, 64);
        if (lane >= o) s += u;
    }
    if (lane == 63) wsum[wv] = s;
    __syncthreads();
    int add = 0;
    for (int w = 0; w < wv; ++w) add += wsum[w];
    cbase[t + 1] = s + add;
    if (t == 0) cbase[0] = 0;
    gcur[t] = s + add - v;
}

// ---------------- pass C: coarse multisplit scatter ----------------
#define CCHUNK 4096
__global__ __launch_bounds__(256) void coarse_scatter_kernel(
    const int* __restrict__ src, const int* __restrict__ dst,
    int* __restrict__ gcur, unsigned int* __restrict__ centries, int E)
{
    __shared__ int h[256];
    __shared__ int base[256];
    __shared__ unsigned int stage[CCHUNK];
    const int t = threadIdx.x;
    const int e0 = blockIdx.x * CCHUNK;
    h[t] = 0;
    __syncthreads();
#pragma unroll
    for (int i = 0; i < 16; ++i) {
        int e = e0 + i * 256 + t;
        unsigned int u = 0xFFFFFFFFu;
        if (e < E) {
            int d = dst[e];
            int s = src[e];
            int b = d >> 8;
            u = ((unsigned)b << 24) | ((unsigned)s << 8) | (unsigned)(d & 255);
            atomicAdd(&h[b], 1);
        }
        stage[i * 256 + t] = u;
    }
    __syncthreads();
    base[t] = atomicAdd(&gcur[t], h[t]);
    __syncthreads();
    h[t] = 0;
    __syncthreads();
#pragma unroll
    for (int i = 0; i < 16; ++i) {
        unsigned int u = stage[i * 256 + t];
        if (u != 0xFFFFFFFFu) {
            int b = u >> 24;
            int r = atomicAdd(&h[b], 1);
            centries[base[b] + r] = u & 0x00FFFFFFu;
        }
    }
}

// ---------------- pass D: fine bucket (one block per coarse bucket) ----------------
#define DCAP 8192
__global__ __launch_bounds__(256) void fine_bucket_kernel(
    const unsigned int* __restrict__ centries,
    const int* __restrict__ cbase,
    int* __restrict__ offo, int* __restrict__ csr, int N, int E)
{
    __shared__ int h[256], ex[256], wsum[4];
    __shared__ int stg[DCAP];
    const int t = threadIdx.x, lane = t & 63, wv = t >> 6;
    const int b = blockIdx.x;
    const int s0 = cbase[b];
    const int cnt = cbase[b + 1] - s0;
    h[t] = 0;
    __syncthreads();
    for (int i = t; i < cnt; i += 256)
        atomicAdd(&h[centries[s0 + i] & 255], 1);
    __syncthreads();
    int v = h[t], s = v;
#pragma unroll
    for (int o = 1; o < 64; o <<= 1) {
        int u = __shfl_up(s, o, 64);
        if (lane >= o) s += u;
    }
    if (lane == 63) wsum[wv] = s;
    __syncthreads();
    int add = 0;
    for (int w = 0; w < wv; ++w) add += wsum[w];
    const int exc = s + add - v;
    ex[t] = exc;
    const int dg = b * 256 + t;
    if (dg < N) offo[dg] = s0 + exc;
    if (b == 0 && t == 0) offo[N] = E;
    h[t] = 0;
    __syncthreads();
    if (cnt <= DCAP) {
        for (int i = t; i < cnt; i += 256) {
            unsigned int u = centries[s0 + i];
            int dl = u & 255;
            int r = atomicAdd(&h[dl], 1);
            stg[ex[dl] + r] = (int)(u >> 8);
        }
        __syncthreads();
        for (int i = t; i < cnt; i += 256)
            csr[s0 + i] = stg[i];
    } else {
        for (int i = t; i < cnt; i += 256) {
            unsigned int u = centries[s0 + i];
            int dl = u & 255;
            int r = atomicAdd(&h[dl], 1);
            csr[s0 + ex[dl] + r] = (int)(u >> 8);
        }
    }
}

// ---------------- sliced gather-mean (XCD-pinned, L2-resident, nt-hygiene) ----------------
// Table is [4][N][32] bf16; slice = 3.2MB < 4MB per-XCD L2. Slice s handled
// only by blocks with blockIdx%8 in {2s,2s+1} (round-robin wg->XCD dispatch).
// nt-hygiene: csr idx loads + agg frag stores are NONTEMPORAL so the only
// L2-resident stream is the pinned feature slice (r9 lesson: streaming
// agg/csr through L2 thrashed the slice). Overshoot idx clamped to row 0
// (hot line); guards zero the contributions -> numerics bit-identical.
__global__ __launch_bounds__(256) void gather_slice_kernel(
    const unsigned short* __restrict__ featsl,    // [4][N][32] bf16 hi
    const int* __restrict__ off,
    const int* __restrict__ csr,
    unsigned short* __restrict__ agg_hi,
    unsigned short* __restrict__ agg_lo,
    int N, int ntiles)
{
    const int bid = blockIdx.x;
    const int s = (bid & 7) >> 1;                     // slice -> XCD pair
    const int k = ((bid >> 3) << 1) | (bid & 1);      // 64-node tile index
    const int w = threadIdx.x >> 6, l = threadIdx.x & 63;
    const int t16 = k * 4 + w;                        // global 16-node tile
    if (t16 >= ntiles) return;
    const int gn = l >> 2, q2 = l & 3;
    const int node = t16 * 16 + gn;
    const int start = off[node];
    const int end   = off[node + 1];
    const unsigned short* fb = featsl + (size_t)s * N * 32 + q2 * 8;

    float ga[8] = {0.f, 0.f, 0.f, 0.f, 0.f, 0.f, 0.f, 0.f};

#define LDIX(dst, be)                                                      \
    { int4v t_ = __builtin_nontemporal_load((const int4v*)(csr + (be)));   \
      dst.x = ((be)     < end) ? t_.x : 0;                                 \
      dst.y = ((be) + 1 < end) ? t_.y : 0;                                 \
      dst.z = ((be) + 2 < end) ? t_.z : 0;                                 \
      dst.w = ((be) + 3 < end) ? t_.w : 0; }

#define ACC(rv)                                                         \
    { ga[0] += bfhi(rv.x); ga[1] += bflo(rv.x);                         \
      ga[2] += bfhi(rv.y); ga[3] += bflo(rv.y);                         \
      ga[4] += bfhi(rv.z); ga[5] += bflo(rv.z);                         \
      ga[6] += bfhi(rv.w); ga[7] += bflo(rv.w); }

    if (start < end) {
        int4v ix;
        LDIX(ix, start);
        uint4v c0 = *(const uint4v*)(fb + (size_t)ix.x * 32);
        uint4v c1 = *(const uint4v*)(fb + (size_t)ix.y * 32);
        uint4v c2 = *(const uint4v*)(fb + (size_t)ix.z * 32);
        uint4v c3 = *(const uint4v*)(fb + (size_t)ix.w * 32);
        for (int e = start; e < end; e += 4) {
            int4v ixn;
            LDIX(ixn, e + 4);                          // pad-safe (csr padded 32)
            uint4v n0 = *(const uint4v*)(fb + (size_t)ixn.x * 32);
            uint4v n1 = *(const uint4v*)(fb + (size_t)ixn.y * 32);
            uint4v n2 = *(const uint4v*)(fb + (size_t)ixn.z * 32);
            uint4v n3 = *(const uint4v*)(fb + (size_t)ixn.w * 32);
            if (e + 1 >= end) c1 = (uint4v)0u;
            if (e + 2 >= end) c2 = (uint4v)0u;
            if (e + 3 >= end) c3 = (uint4v)0u;
            ACC(c0) ACC(c1) ACC(c2) ACC(c3)
            c0 = n0; c1 = n1; c2 = n2; c3 = n3;
        }
    }
#undef ACC
#undef LDIX

    // mean + bf16 hi/lo split -> packed frag (ks = slice), nt stores
    const float dinv = 1.0f / (float)max(end - start, 1);
    short8 hi8, lo8;
#pragma unroll
    for (int c = 0; c < 8; ++c) {
        float v = ga[c] * dinv;
        unsigned int hb = f2bf_bits(v);
        hi8[c] = (short)hb;
        lo8[c] = (short)f2bf_bits(v - __uint_as_float(hb << 16));
    }
    const size_t p = ((size_t)(t16 * 4 + s) * 64 + q2 * 16 + gn) * 8;
    __builtin_nontemporal_store(hi8, (short8*)(agg_hi + p));
    __builtin_nontemporal_store(lo8, (short8*)(agg_lo + p));
}

// ---------------- dense MFMA GEMM: out = agg@Wl + self@Wr + b ----------------
// Block = one 16-node tile, 4 waves; wave w computes output col-blocks
// t=2w,2w+1. All read-once streams (agg, self) loaded NONTEMPORAL, output
// stored NONTEMPORAL; only the weights (reused by all blocks) occupy L2.
__global__ __launch_bounds__(256, 4) void sage_gemm_kernel(
    const unsigned short* __restrict__ agg_hi,
    const unsigned short* __restrict__ agg_lo,
    const unsigned short* __restrict__ selfsl_hi,  // [4][N][32]
    const unsigned short* __restrict__ selfsl_lo,
    const unsigned short* __restrict__ wpk_hi,
    const unsigned short* __restrict__ wpk_lo,
    const float* __restrict__ bias,
    unsigned short* __restrict__ outsl_hi,         // [4][N][32]
    unsigned short* __restrict__ outsl_lo,         // nullable
    int N, int do_relu)
{
    __shared__ unsigned short outs_hi[16][128];
    __shared__ unsigned short outs_lo[16][128];

    const int w = threadIdx.x >> 6;
    const int l = threadIdx.x & 63;
    const int tile = blockIdx.x;
    const int n0w = tile * 16;
    const int q = l >> 4, r16 = l & 15;
    const int mnode = n0w + r16;

    f32x4 acc0 = {0.f, 0.f, 0.f, 0.f};
    f32x4 acc1 = {0.f, 0.f, 0.f, 0.f};
    const unsigned short* aph = agg_hi + (size_t)tile * 2048 + l * 8;
    const unsigned short* apl = agg_lo + (size_t)tile * 2048 + l * 8;
    const unsigned short* bh0 = wpk_hi + (size_t)(2 * w) * 4096 + l * 8;
    const unsigned short* bl0 = wpk_lo + (size_t)(2 * w) * 4096 + l * 8;

#pragma unroll
    for (int ks = 0; ks < 8; ++ks) {
        short8 AH, AL;
        if (ks < 4) {
            AH = __builtin_nontemporal_load((const short8*)(aph + ks * 512));
            AL = __builtin_nontemporal_load((const short8*)(apl + ks * 512));
        } else {
            const size_t so = (size_t)(ks - 4) * N * 32 + (size_t)mnode * 32 + q * 8;
            AH = __builtin_nontemporal_load((const short8*)(selfsl_hi + so));
            AL = __builtin_nontemporal_load((const short8*)(selfsl_lo + so));
        }
        short8 BH0 = *(const short8*)(bh0 + ks * 512);
        short8 BL0 = *(const short8*)(bl0 + ks * 512);
        short8 BH1 = *(const short8*)(bh0 + 4096 + ks * 512);
        short8 BL1 = *(const short8*)(bl0 + 4096 + ks * 512);
        acc0 = __builtin_amdgcn_mfma_f32_16x16x32_bf16(AH, BH0, acc0, 0, 0, 0);
        acc0 = __builtin_amdgcn_mfma_f32_16x16x32_bf16(AL, BH0, acc0, 0, 0, 0);
        acc0 = __builtin_amdgcn_mfma_f32_16x16x32_bf16(AH, BL0, acc0, 0, 0, 0);
        acc1 = __builtin_amdgcn_mfma_f32_16x16x32_bf16(AH, BH1, acc1, 0, 0, 0);
        acc1 = __builtin_amdgcn_mfma_f32_16x16x32_bf16(AL, BH1, acc1, 0, 0, 0);
        acc1 = __builtin_amdgcn_mfma_f32_16x16x32_bf16(AH, BL1, acc1, 0, 0, 0);
    }

    // epilogue: bias/relu/split -> LDS tile
    {
        const float bv0 = bias[32 * w + r16];
        const float bv1 = bias[32 * w + 16 + r16];
#pragma unroll
        for (int r = 0; r < 4; ++r) {
            float v0 = acc0[r] + bv0;
            float v1 = acc1[r] + bv1;
            if (do_relu) { v0 = fmaxf(v0, 0.f); v1 = fmaxf(v1, 0.f); }
            const int row = q * 4 + r;
            unsigned int h0 = f2bf_bits(v0);
            unsigned int h1 = f2bf_bits(v1);
            outs_hi[row][32 * w + r16] = (unsigned short)h0;
            outs_hi[row][32 * w + 16 + r16] = (unsigned short)h1;
            outs_lo[row][32 * w + r16] =
                (unsigned short)f2bf_bits(v0 - __uint_as_float(h0 << 16));
            outs_lo[row][32 * w + 16 + r16] =
                (unsigned short)f2bf_bits(v1 - __uint_as_float(h1 << 16));
        }
    }
    __syncthreads();
    // stream to sliced layout: tid -> (row, 16B chunk); full 64B lines/node; nt
    {
        const int tid = threadIdx.x;
        const int row = tid >> 4, ch8 = tid & 15;
        const size_t o = (size_t)(ch8 >> 2) * N * 32
                       + (size_t)(n0w + row) * 32 + (ch8 & 3) * 8;
        short8 vh = *(short8*)(&outs_hi[row][ch8 * 8]);
        __builtin_nontemporal_store(vh, (short8*)(outsl_hi + o));
        if (outsl_lo) {
            short8 vl = *(short8*)(&outs_lo[row][ch8 * 8]);
            __builtin_nontemporal_store(vl, (short8*)(outsl_lo + o));
        }
    }
}

// ---------------- edge dot-product decode (sliced bf16 z) ----------------
// 16 lanes per edge, 16 B loads, reduce depth 4.
__global__ __launch_bounds__(256) void pred_kernel(const unsigned short* __restrict__ zsl,
                                                   const int* __restrict__ ps,
                                                   const int* __restrict__ pd,
                                                   float* __restrict__ out, int N, int EP) {
    int idx = blockIdx.x * 256 + threadIdx.x;
    int e = idx >> 4;
    if (e >= EP) return;
    int L = idx & 15;
    const unsigned short* fb = zsl + (size_t)(L >> 2) * N * 32 + (L & 3) * 8;
    uint4 ra = *(const uint4*)(fb + (size_t)ps[e] * 32);
    uint4 rb = *(const uint4*)(fb + (size_t)pd[e] * 32);
    float p = bfhi(ra.x) * bfhi(rb.x) + bflo(ra.x) * bflo(rb.x)
            + bfhi(ra.y) * bfhi(rb.y) + bflo(ra.y) * bflo(rb.y)
            + bfhi(ra.z) * bfhi(rb.z) + bflo(ra.z) * bflo(rb.z)
            + bfhi(ra.w) * bfhi(rb.w) + bflo(ra.w) * bflo(rb.w);
#pragma unroll
    for (int off = 8; off > 0; off >>= 1) p += __shfl_xor(p, off, 16);
    if (L == 0) out[e] = p;
}

extern "C" void kernel_launch(void* const* d_in, const int* in_sizes, int n_in,
                              void* d_out, int out_size, void* d_ws, size_t ws_size,
                              hipStream_t stream) {
    const float* x   = (const float*)d_in[0];
    const float* W1l = (const float*)d_in[1];
    const float* b1  = (const float*)d_in[2];
    const float* W1r = (const float*)d_in[3];
    const float* W2l = (const float*)d_in[4];
    const float* b2  = (const float*)d_in[5];
    const float* W2r = (const float*)d_in[6];
    const int* edge_index = (const int*)d_in[7];
    const int* pred_edges = (const int*)d_in[8];
    float* out = (float*)d_out;

    const int N  = in_sizes[0] / D;   // 50000
    const int E  = in_sizes[7] / 2;   // 800000
    const int EP = in_sizes[8] / 2;   // 200000

    const int* src = edge_index;
    const int* dst = edge_index + E;
    const int* ps  = pred_edges;
    const int* pd  = pred_edges + EP;

    // workspace layout
    int* chist   = (int*)d_ws;                 // 256
    int* cbase   = chist + 256;                // 257 (pad 272)
    int* gcur    = cbase + 272;                // 256
    int* off     = gcur + 256;                 // N+1 (pad 50016)
    unsigned int* centries = (unsigned int*)(off + 50016);  // E
    int* csr     = (int*)(centries + E);       // E + 32 pad
    unsigned short* w1_hi = (unsigned short*)(csr + E + 32);
    unsigned short* w1_lo = w1_hi + 32768;
    unsigned short* w2_hi = w1_lo + 32768;
    unsigned short* w2_lo = w2_hi + 32768;
    unsigned short* xsl_hi = w2_lo + 32768;           // [4][N][32] bf16
    unsigned short* xsl_lo = xsl_hi + (size_t)N * D;
    unsigned short* hsl_hi = xsl_lo + (size_t)N * D;
    unsigned short* hsl_lo = hsl_hi + (size_t)N * D;
    unsigned short* zsl    = hsl_lo + (size_t)N * D;
    unsigned short* agg_hi = zsl + (size_t)N * D;     // packed A-frags
    unsigned short* agg_lo = agg_hi + (size_t)N * D;

    const int n4 = N * D / 4;
    const int ncast = (n4 + 255) / 256;             // 6250
    const int ntiles = N / 16;                      // 3125
    const int nblk_gather = ((ntiles + 3) / 4) * 4; // 3128 = 8 x 391 (slice-pinned)
    const int nbC = (E + CCHUNK - 1) / CCHUNK;      // 196
    const int nbD = (N + 255) / 256;                // 196
    const int nblk_pred = (EP * 16 + 255) / 256;    // 12500

    // fused prep: x sliced hi/lo cast + weight pack + zero chist & csr pad
    prep_kernel<<<ncast + 257, 256, 0, stream>>>(x, W1l, W1r, W2l, W2r,
                                                 xsl_hi, xsl_lo, w1_hi, w1_lo, w2_hi, w2_lo,
                                                 n4, ncast, N, chist, csr + E);

    // CSR build: coarse count -> scan -> coarse multisplit -> fine bucket
    coarse_count_kernel<<<256, 256, 0, stream>>>(dst, chist, E);
    scan256_kernel<<<1, 256, 0, stream>>>(chist, cbase, gcur);
    coarse_scatter_kernel<<<nbC, 256, 0, stream>>>(src, dst, gcur, centries, E);
    fine_bucket_kernel<<<nbD, 256, 0, stream>>>(centries, cbase, off, csr, N, E);

    // layer 1
    gather_slice_kernel<<<nblk_gather, 256, 0, stream>>>(xsl_hi, off, csr,
                                                         agg_hi, agg_lo, N, ntiles);
    sage_gemm_kernel<<<ntiles, 256, 0, stream>>>(agg_hi, agg_lo, xsl_hi, xsl_lo,
                                                 w1_hi, w1_lo, b1, hsl_hi, hsl_lo, N, 1);
    // layer 2
    gather_slice_kernel<<<nblk_gather, 256, 0, stream>>>(hsl_hi, off, csr,
                                                         agg_hi, agg_lo, N, ntiles);
    sage_gemm_kernel<<<ntiles, 256, 0, stream>>>(agg_hi, agg_lo, hsl_hi, hsl_lo,
                                                 w2_hi, w2_lo, b2, zsl,
                                                 (unsigned short*)nullptr, N, 0);
    // decode
    pred_kernel<<<nblk_pred, 256, 0, stream>>>(zsl, ps, pd, out, N, EP);
}

// Round 11
// 255.400 us; speedup vs baseline: 1.2292x; 1.2292x over previous
//
#include <hip/hip_runtime.h>

#define D 128

typedef __attribute__((ext_vector_type(8))) short short8;
typedef __attribute__((ext_vector_type(4))) float f32x4;

// fp32 -> bf16 bits, round-to-nearest-even
__device__ inline unsigned int f2bf_bits(float f) {
    unsigned int u = __float_as_uint(f);
    return (u + 0x7FFFu + ((u >> 16) & 1u)) >> 16;
}

__device__ inline float bfhi(unsigned int u) { return __uint_as_float(u << 16); }
__device__ inline float bflo(unsigned int u) { return __uint_as_float(u & 0xffff0000u); }

// ---------------- fused prep: x cast + weight pack + coarse count + pad zero ----------------
// Branch by blockIdx: [0,ncast) cast x->bf16 hi/lo row-major; [ncast,ncast+256)
// weight pack; [ncast+256,ncast+512) per-block coarse histograms into
// chist2[cb][256] (each slot written exactly once -> no pre-zeroing, no race);
// last block zeroes the csr pad.
__global__ __launch_bounds__(256) void prep_kernel(
    const float* __restrict__ x,
    const float* __restrict__ W1l, const float* __restrict__ W1r,
    const float* __restrict__ W2l, const float* __restrict__ W2r,
    const int* __restrict__ dst, int E,
    unsigned short* __restrict__ xbf, unsigned short* __restrict__ xlo,
    unsigned short* __restrict__ h1, unsigned short* __restrict__ l1,
    unsigned short* __restrict__ h2, unsigned short* __restrict__ l2,
    int n4, int ncast, int* __restrict__ chist2, int* __restrict__ csrpad)
{
    __shared__ int h[256];
    const int b = blockIdx.x;
    const int t = threadIdx.x;
    if (b < ncast) {
        int i = b * 256 + t;
        if (i >= n4) return;
        f32x4 v = *(const f32x4*)(x + (size_t)i * 4);
        ushort4 oh, ol;
        {
            unsigned int hb; float hf;
            hb = f2bf_bits(v.x); hf = __uint_as_float(hb << 16);
            oh.x = (unsigned short)hb; ol.x = (unsigned short)f2bf_bits(v.x - hf);
            hb = f2bf_bits(v.y); hf = __uint_as_float(hb << 16);
            oh.y = (unsigned short)hb; ol.y = (unsigned short)f2bf_bits(v.y - hf);
            hb = f2bf_bits(v.z); hf = __uint_as_float(hb << 16);
            oh.z = (unsigned short)hb; ol.z = (unsigned short)f2bf_bits(v.z - hf);
            hb = f2bf_bits(v.w); hf = __uint_as_float(hb << 16);
            oh.w = (unsigned short)hb; ol.w = (unsigned short)f2bf_bits(v.w - hf);
        }
        *(ushort4*)(xbf + (size_t)i * 4) = oh;
        *(ushort4*)(xlo + (size_t)i * 4) = ol;
    } else if (b < ncast + 256) {
        // weight pack: B-frag order + bf16 hi/lo split
        int gidx = (b - ncast) * 256 + t;   // 0..65535
        int sel = gidx >> 15;
        int idx = gidx & 32767;
        int tt = idx >> 12;
        int ks = (idx >> 9) & 7;
        int lane = (idx >> 3) & 63;
        int j = idx & 7;
        int qq = lane >> 4, r16 = lane & 15;
        int k = ks * 32 + qq * 8 + j;
        int c = tt * 16 + r16;
        const float* Wl = sel ? W2l : W1l;
        const float* Wr = sel ? W2r : W1r;
        float v = (k < 128) ? Wl[k * 128 + c] : Wr[(k - 128) * 128 + c];
        unsigned int hb = f2bf_bits(v);
        float hf = __uint_as_float(hb << 16);
        unsigned int l = f2bf_bits(v - hf);
        (sel ? h2 : h1)[idx] = (unsigned short)hb;
        (sel ? l2 : l1)[idx] = (unsigned short)l;
    } else if (b < ncast + 512) {
        // coarse histogram (bucket = dst>>8), per-block row in chist2
        const int cb = b - ncast - 256;
        h[t] = 0;
        __syncthreads();
        for (int e = cb * 256 + t; e < E; e += 65536)
            atomicAdd(&h[dst[e] >> 8], 1);
        __syncthreads();
        chist2[cb * 256 + t] = h[t];
    } else {
        if (t < 32) csrpad[t] = 0;
    }
}

// ---------------- pass B: reduce chist2 + scan -> cbase (excl, 257) + gcur ----------------
__global__ __launch_bounds__(256) void scan256_kernel(const int* __restrict__ chist2,
                                                      int* __restrict__ cbase,
                                                      int* __restrict__ gcur) {
    __shared__ int wsum[4];
    const int t = threadIdx.x, lane = t & 63, wv = t >> 6;
    int v = 0;
#pragma unroll 8
    for (int b = 0; b < 256; ++b) v += chist2[b * 256 + t];   // coalesced per row
    int s = v;
#pragma unroll
    for (int o = 1; o < 64; o <<= 1) {
        int u = __shfl_up(s, o, 64);
        if (lane >= o) s += u;
    }
    if (lane == 63) wsum[wv] = s;
    __syncthreads();
    int add = 0;
    for (int w = 0; w < wv; ++w) add += wsum[w];
    cbase[t + 1] = s + add;
    if (t == 0) cbase[0] = 0;
    gcur[t] = s + add - v;
}

// ---------------- pass C: coarse multisplit scatter ----------------
#define CCHUNK 4096
__global__ __launch_bounds__(256) void coarse_scatter_kernel(
    const int* __restrict__ src, const int* __restrict__ dst,
    int* __restrict__ gcur, unsigned int* __restrict__ centries, int E)
{
    __shared__ int h[256];
    __shared__ int base[256];
    __shared__ unsigned int stage[CCHUNK];
    const int t = threadIdx.x;
    const int e0 = blockIdx.x * CCHUNK;
    h[t] = 0;
    __syncthreads();
#pragma unroll
    for (int i = 0; i < 16; ++i) {
        int e = e0 + i * 256 + t;
        unsigned int u = 0xFFFFFFFFu;
        if (e < E) {
            int d = dst[e];
            int s = src[e];
            int b = d >> 8;
            u = ((unsigned)b << 24) | ((unsigned)s << 8) | (unsigned)(d & 255);
            atomicAdd(&h[b], 1);
        }
        stage[i * 256 + t] = u;
    }
    __syncthreads();
    base[t] = atomicAdd(&gcur[t], h[t]);
    __syncthreads();
    h[t] = 0;
    __syncthreads();
#pragma unroll
    for (int i = 0; i < 16; ++i) {
        unsigned int u = stage[i * 256 + t];
        if (u != 0xFFFFFFFFu) {
            int b = u >> 24;
            int r = atomicAdd(&h[b], 1);
            centries[base[b] + r] = u & 0x00FFFFFFu;
        }
    }
}

// ---------------- pass D: fine bucket (one block per coarse bucket) ----------------
#define DCAP 8192
__global__ __launch_bounds__(256) void fine_bucket_kernel(
    const unsigned int* __restrict__ centries,
    const int* __restrict__ cbase,
    int* __restrict__ offo, int* __restrict__ csr, int N, int E)
{
    __shared__ int h[256], ex[256], wsum[4];
    __shared__ int stg[DCAP];
    const int t = threadIdx.x, lane = t & 63, wv = t >> 6;
    const int b = blockIdx.x;
    const int s0 = cbase[b];
    const int cnt = cbase[b + 1] - s0;
    h[t] = 0;
    __syncthreads();
    for (int i = t; i < cnt; i += 256)
        atomicAdd(&h[centries[s0 + i] & 255], 1);
    __syncthreads();
    int v = h[t], s = v;
#pragma unroll
    for (int o = 1; o < 64; o <<= 1) {
        int u = __shfl_up(s, o, 64);
        if (lane >= o) s += u;
    }
    if (lane == 63) wsum[wv] = s;
    __syncthreads();
    int add = 0;
    for (int w = 0; w < wv; ++w) add += wsum[w];
    const int exc = s + add - v;
    ex[t] = exc;
    const int dg = b * 256 + t;
    if (dg < N) offo[dg] = s0 + exc;
    if (b == 0 && t == 0) offo[N] = E;
    h[t] = 0;
    __syncthreads();
    if (cnt <= DCAP) {
        for (int i = t; i < cnt; i += 256) {
            unsigned int u = centries[s0 + i];
            int dl = u & 255;
            int r = atomicAdd(&h[dl], 1);
            stg[ex[dl] + r] = (int)(u >> 8);
        }
        __syncthreads();
        for (int i = t; i < cnt; i += 256)
            csr[s0 + i] = stg[i];
    } else {
        for (int i = t; i < cnt; i += 256) {
            unsigned int u = centries[s0 + i];
            int dl = u & 255;
            int r = atomicAdd(&h[dl], 1);
            csr[s0 + ex[dl] + r] = (int)(u >> 8);
        }
    }
}

// ---------------- fused gather-mean + MFMA GEMM (4 waves per tile) ----------------
// EXACT round-5 structure (best measured: 55.9us, FETCH 96MB, occ 60%).
// Block = 256 threads = 4 waves, one 16-node tile. Wave w covers channels
// [w*32, w*32+32): lane (gn=l>>2, q2=l&3) accumulates 8 channels of node gn
// (one uint4/edge, depth-2 copy-chain). Overshoot reads next-node edges =
// lines adjacent lanes fetch anyway (effective prefetch, not waste). All 4
// waves iterate the same edge lists -> no straggler tail. A-frags exchanged
// via LDS; wave w computes output col-blocks t=2w,2w+1; epilogue stages in
// LDS, streams coalesced.
__global__ __launch_bounds__(256, 4) void fused_sage_kernel(
    const unsigned short* __restrict__ featbf,    // gather table (bf16 hi), row-major
    const int* __restrict__ off,
    const int* __restrict__ csr,
    const unsigned short* __restrict__ self_hi,   // row-major bf16 (hi)
    const unsigned short* __restrict__ self_lo,   // row-major bf16 (lo)
    const unsigned short* __restrict__ wpk_hi,
    const unsigned short* __restrict__ wpk_lo,
    const float* __restrict__ bias,
    unsigned short* __restrict__ out_hi,          // row-major bf16
    unsigned short* __restrict__ out_lo,          // nullable (layer-1 h lo)
    int do_relu)
{
    __shared__ unsigned short AHs[4][64][8];      // [ks][mfma-lane][j]
    __shared__ unsigned short ALs[4][64][8];
    __shared__ unsigned short outs_hi[16][128];
    __shared__ unsigned short outs_lo[16][128];

    const int w = threadIdx.x >> 6;               // wave 0..3
    const int l = threadIdx.x & 63;
    const int tile = blockIdx.x;
    const int n0w = tile * 16;

    // ---- gather phase ----
    const int gn = l >> 2;                        // node 0..15
    const int q2 = l & 3;                         // channel sub-block
    const int gnode = n0w + gn;
    const int start = off[gnode];
    const int end   = off[gnode + 1];
    const unsigned short* fb = featbf + w * 32 + q2 * 8;

    float ga[8] = {0.f, 0.f, 0.f, 0.f, 0.f, 0.f, 0.f, 0.f};

#define ACC(rv)                                                         \
    { ga[0] += bfhi(rv.x); ga[1] += bflo(rv.x);                         \
      ga[2] += bfhi(rv.y); ga[3] += bflo(rv.y);                         \
      ga[4] += bfhi(rv.z); ga[5] += bflo(rv.z);                         \
      ga[6] += bfhi(rv.w); ga[7] += bflo(rv.w); }

    const uint4 zero4 = {0u, 0u, 0u, 0u};
    if (start < end) {
        int4 ix = *(const int4*)(csr + start);
        uint4 c0 = *(const uint4*)(fb + (size_t)ix.x * D);
        uint4 c1 = *(const uint4*)(fb + (size_t)ix.y * D);
        uint4 c2 = *(const uint4*)(fb + (size_t)ix.z * D);
        uint4 c3 = *(const uint4*)(fb + (size_t)ix.w * D);
        for (int e = start; e < end; e += 4) {
            // depth-2: issue next batch (pad-safe overshoot) before accumulating
            int4 ixn = *(const int4*)(csr + e + 4);
            uint4 n0 = *(const uint4*)(fb + (size_t)ixn.x * D);
            uint4 n1 = *(const uint4*)(fb + (size_t)ixn.y * D);
            uint4 n2 = *(const uint4*)(fb + (size_t)ixn.z * D);
            uint4 n3 = *(const uint4*)(fb + (size_t)ixn.w * D);
            if (e + 1 >= end) c1 = zero4;
            if (e + 2 >= end) c2 = zero4;
            if (e + 3 >= end) c3 = zero4;
            ACC(c0) ACC(c1) ACC(c2) ACC(c3)
            c0 = n0; c1 = n1; c2 = n2; c3 = n3;
        }
    }
#undef ACC

    // mean + bf16 hi/lo split -> LDS frag exchange
    {
        const float dinv = 1.0f / (float)max(end - start, 1);
        short8 hi8, lo8;
#pragma unroll
        for (int c = 0; c < 8; ++c) {
            float v = ga[c] * dinv;
            unsigned int hb = f2bf_bits(v);
            hi8[c] = (short)hb;
            lo8[c] = (short)f2bf_bits(v - __uint_as_float(hb << 16));
        }
        // MFMA lane (q=q2, r16=gn) consumes this as frag ks=w
        *(short8*)&AHs[w][q2 * 16 + gn][0] = hi8;
        *(short8*)&ALs[w][q2 * 16 + gn][0] = lo8;
    }
    __syncthreads();

    // ---- MFMA phase: wave w computes t = 2w, 2w+1 ----
    const int q = l >> 4, r16 = l & 15;
    const int mnode = n0w + r16;
    f32x4 acc0 = {0.f, 0.f, 0.f, 0.f};
    f32x4 acc1 = {0.f, 0.f, 0.f, 0.f};
    const unsigned short* sph = self_hi + (size_t)mnode * D + q * 8;
    const unsigned short* spl = self_lo + (size_t)mnode * D + q * 8;
    const unsigned short* bh0 = wpk_hi + (size_t)(2 * w) * 4096 + l * 8;
    const unsigned short* bl0 = wpk_lo + (size_t)(2 * w) * 4096 + l * 8;

#pragma unroll
    for (int ks = 0; ks < 8; ++ks) {
        short8 AH, AL;
        if (ks < 4) {
            AH = *(const short8*)&AHs[ks][l][0];
            AL = *(const short8*)&ALs[ks][l][0];
        } else {
            AH = *(const short8*)(sph + (ks - 4) * 32);
            AL = *(const short8*)(spl + (ks - 4) * 32);
        }
        short8 BH0 = *(const short8*)(bh0 + ks * 512);
        short8 BL0 = *(const short8*)(bl0 + ks * 512);
        short8 BH1 = *(const short8*)(bh0 + 4096 + ks * 512);
        short8 BL1 = *(const short8*)(bl0 + 4096 + ks * 512);
        acc0 = __builtin_amdgcn_mfma_f32_16x16x32_bf16(AH, BH0, acc0, 0, 0, 0);
        acc0 = __builtin_amdgcn_mfma_f32_16x16x32_bf16(AL, BH0, acc0, 0, 0, 0);
        acc0 = __builtin_amdgcn_mfma_f32_16x16x32_bf16(AH, BL0, acc0, 0, 0, 0);
        acc1 = __builtin_amdgcn_mfma_f32_16x16x32_bf16(AH, BH1, acc1, 0, 0, 0);
        acc1 = __builtin_amdgcn_mfma_f32_16x16x32_bf16(AL, BH1, acc1, 0, 0, 0);
        acc1 = __builtin_amdgcn_mfma_f32_16x16x32_bf16(AH, BL1, acc1, 0, 0, 0);
    }

    // ---- epilogue: bias/relu/split -> LDS tile -> coalesced stream ----
    {
        const float bv0 = bias[32 * w + r16];
        const float bv1 = bias[32 * w + 16 + r16];
#pragma unroll
        for (int r = 0; r < 4; ++r) {
            float v0 = acc0[r] + bv0;
            float v1 = acc1[r] + bv1;
            if (do_relu) { v0 = fmaxf(v0, 0.f); v1 = fmaxf(v1, 0.f); }
            const int row = q * 4 + r;
            unsigned int h0 = f2bf_bits(v0);
            unsigned int h1 = f2bf_bits(v1);
            outs_hi[row][32 * w + r16] = (unsigned short)h0;
            outs_hi[row][32 * w + 16 + r16] = (unsigned short)h1;
            outs_lo[row][32 * w + r16] =
                (unsigned short)f2bf_bits(v0 - __uint_as_float(h0 << 16));
            outs_lo[row][32 * w + 16 + r16] =
                (unsigned short)f2bf_bits(v1 - __uint_as_float(h1 << 16));
        }
    }
    __syncthreads();
    {
        const int tid = threadIdx.x;
        short8 vh = *(short8*)(&outs_hi[0][0] + tid * 8);
        *(short8*)(out_hi + (size_t)n0w * D + tid * 8) = vh;
        if (out_lo) {
            short8 vl = *(short8*)(&outs_lo[0][0] + tid * 8);
            *(short8*)(out_lo + (size_t)n0w * D + tid * 8) = vl;
        }
    }
}

// ---------------- edge dot-product decode (bf16 z rows) ----------------
// 16 lanes per edge, 16 B loads, reduce depth 4.
__global__ __launch_bounds__(256) void pred_kernel(const unsigned short* __restrict__ zbf,
                                                   const int* __restrict__ ps,
                                                   const int* __restrict__ pd,
                                                   float* __restrict__ out, int EP) {
    int idx = blockIdx.x * 256 + threadIdx.x;
    int e = idx >> 4;
    if (e >= EP) return;
    int L = idx & 15;
    const unsigned short* fb = zbf + (size_t)L * 8;
    uint4 ra = *(const uint4*)(fb + (size_t)ps[e] * D);
    uint4 rb = *(const uint4*)(fb + (size_t)pd[e] * D);
    float p = bfhi(ra.x) * bfhi(rb.x) + bflo(ra.x) * bflo(rb.x)
            + bfhi(ra.y) * bfhi(rb.y) + bflo(ra.y) * bflo(rb.y)
            + bfhi(ra.z) * bfhi(rb.z) + bflo(ra.z) * bflo(rb.z)
            + bfhi(ra.w) * bfhi(rb.w) + bflo(ra.w) * bflo(rb.w);
#pragma unroll
    for (int off = 8; off > 0; off >>= 1) p += __shfl_xor(p, off, 16);
    if (L == 0) out[e] = p;
}

extern "C" void kernel_launch(void* const* d_in, const int* in_sizes, int n_in,
                              void* d_out, int out_size, void* d_ws, size_t ws_size,
                              hipStream_t stream) {
    const float* x   = (const float*)d_in[0];
    const float* W1l = (const float*)d_in[1];
    const float* b1  = (const float*)d_in[2];
    const float* W1r = (const float*)d_in[3];
    const float* W2l = (const float*)d_in[4];
    const float* b2  = (const float*)d_in[5];
    const float* W2r = (const float*)d_in[6];
    const int* edge_index = (const int*)d_in[7];
    const int* pred_edges = (const int*)d_in[8];
    float* out = (float*)d_out;

    const int N  = in_sizes[0] / D;   // 50000
    const int E  = in_sizes[7] / 2;   // 800000
    const int EP = in_sizes[8] / 2;   // 200000

    const int* src = edge_index;
    const int* dst = edge_index + E;
    const int* ps  = pred_edges;
    const int* pd  = pred_edges + EP;

    // workspace layout
    int* chist2  = (int*)d_ws;                 // 256 x 256 per-block histograms
    int* cbase   = chist2 + 65536;             // 257 (pad 272)
    int* gcur    = cbase + 272;                // 256
    int* off     = gcur + 256;                 // N+1 (pad 50016)
    unsigned int* centries = (unsigned int*)(off + 50016);  // E
    int* csr     = (int*)(centries + E);       // E + 32 pad
    unsigned short* w1_hi = (unsigned short*)(csr + E + 32);
    unsigned short* w1_lo = w1_hi + 32768;
    unsigned short* w2_hi = w1_lo + 32768;
    unsigned short* w2_lo = w2_hi + 32768;
    unsigned short* xbf   = w2_lo + 32768;          // N*D bf16 (x hi)
    unsigned short* xlo   = xbf + (size_t)N * D;    // N*D bf16 (x lo)
    unsigned short* hbf   = xlo + (size_t)N * D;    // N*D bf16 (h hi)
    unsigned short* hlo   = hbf + (size_t)N * D;    // N*D bf16 (h lo)
    unsigned short* zbf   = hlo + (size_t)N * D;    // N*D bf16 (z)

    const int n4 = N * D / 4;
    const int ncast = (n4 + 255) / 256;             // 6250
    const int ntiles = N / 16;                      // 3125
    const int nbC = (E + CCHUNK - 1) / CCHUNK;      // 196
    const int nbD = (N + 255) / 256;                // 196
    const int nblk_pred = (EP * 16 + 255) / 256;    // 12500

    // fused prep: x hi/lo cast + weight pack + coarse count + csr pad zero
    prep_kernel<<<ncast + 513, 256, 0, stream>>>(x, W1l, W1r, W2l, W2r, dst, E,
                                                 xbf, xlo, w1_hi, w1_lo, w2_hi, w2_lo,
                                                 n4, ncast, chist2, csr + E);

    // CSR build: scan (reduces chist2) -> coarse multisplit -> fine bucket
    scan256_kernel<<<1, 256, 0, stream>>>(chist2, cbase, gcur);
    coarse_scatter_kernel<<<nbC, 256, 0, stream>>>(src, dst, gcur, centries, E);
    fine_bucket_kernel<<<nbD, 256, 0, stream>>>(centries, cbase, off, csr, N, E);

    // layer 1: h = relu(mean(x)@W1l + x@W1r + b1) -> hbf/hlo
    fused_sage_kernel<<<ntiles, 256, 0, stream>>>(xbf, off, csr, xbf, xlo,
                                                  w1_hi, w1_lo, b1, hbf, hlo, 1);
    // layer 2: z = mean(h)@W2l + h@W2r + b2 -> zbf
    fused_sage_kernel<<<ntiles, 256, 0, stream>>>(hbf, off, csr, hbf, hlo,
                                                  w2_hi, w2_lo, b2, zbf,
                                                  (unsigned short*)nullptr, 0);
    // decode from bf16 z
    pred_kernel<<<nblk_pred, 256, 0, stream>>>(zbf, ps, pd, out, EP);
}

// Round 12
// 241.203 us; speedup vs baseline: 1.3015x; 1.0589x over previous
//
#include <hip/hip_runtime.h>

#define D 128

typedef __attribute__((ext_vector_type(8))) short short8;
typedef __attribute__((ext_vector_type(4))) float f32x4;

// fp32 -> bf16 bits, round-to-nearest-even
__device__ inline unsigned int f2bf_bits(float f) {
    unsigned int u = __float_as_uint(f);
    return (u + 0x7FFFu + ((u >> 16) & 1u)) >> 16;
}

__device__ inline float bfhi(unsigned int u) { return __uint_as_float(u << 16); }
__device__ inline float bflo(unsigned int u) { return __uint_as_float(u & 0xffff0000u); }

// ---------------- fused prep: x cast + weight pack + coarse count + pad zero ----------------
// Branch by blockIdx: [0,ncast) cast x->bf16 hi/lo row-major; [ncast,ncast+256)
// weight pack; [ncast+256,ncast+512) per-block coarse histograms into
// chist2[cb][256] (each slot written exactly once -> no pre-zeroing, no race);
// last block zeroes the csr pad.
__global__ __launch_bounds__(256) void prep_kernel(
    const float* __restrict__ x,
    const float* __restrict__ W1l, const float* __restrict__ W1r,
    const float* __restrict__ W2l, const float* __restrict__ W2r,
    const int* __restrict__ dst, int E,
    unsigned short* __restrict__ xbf, unsigned short* __restrict__ xlo,
    unsigned short* __restrict__ h1, unsigned short* __restrict__ l1,
    unsigned short* __restrict__ h2, unsigned short* __restrict__ l2,
    int n4, int ncast, int* __restrict__ chist2, int* __restrict__ csrpad)
{
    __shared__ int h[256];
    const int b = blockIdx.x;
    const int t = threadIdx.x;
    if (b < ncast) {
        int i = b * 256 + t;
        if (i >= n4) return;
        f32x4 v = *(const f32x4*)(x + (size_t)i * 4);
        ushort4 oh, ol;
        {
            unsigned int hb; float hf;
            hb = f2bf_bits(v.x); hf = __uint_as_float(hb << 16);
            oh.x = (unsigned short)hb; ol.x = (unsigned short)f2bf_bits(v.x - hf);
            hb = f2bf_bits(v.y); hf = __uint_as_float(hb << 16);
            oh.y = (unsigned short)hb; ol.y = (unsigned short)f2bf_bits(v.y - hf);
            hb = f2bf_bits(v.z); hf = __uint_as_float(hb << 16);
            oh.z = (unsigned short)hb; ol.z = (unsigned short)f2bf_bits(v.z - hf);
            hb = f2bf_bits(v.w); hf = __uint_as_float(hb << 16);
            oh.w = (unsigned short)hb; ol.w = (unsigned short)f2bf_bits(v.w - hf);
        }
        *(ushort4*)(xbf + (size_t)i * 4) = oh;
        *(ushort4*)(xlo + (size_t)i * 4) = ol;
    } else if (b < ncast + 256) {
        // weight pack: B-frag order + bf16 hi/lo split
        int gidx = (b - ncast) * 256 + t;   // 0..65535
        int sel = gidx >> 15;
        int idx = gidx & 32767;
        int tt = idx >> 12;
        int ks = (idx >> 9) & 7;
        int lane = (idx >> 3) & 63;
        int j = idx & 7;
        int qq = lane >> 4, r16 = lane & 15;
        int k = ks * 32 + qq * 8 + j;
        int c = tt * 16 + r16;
        const float* Wl = sel ? W2l : W1l;
        const float* Wr = sel ? W2r : W1r;
        float v = (k < 128) ? Wl[k * 128 + c] : Wr[(k - 128) * 128 + c];
        unsigned int hb = f2bf_bits(v);
        float hf = __uint_as_float(hb << 16);
        unsigned int l = f2bf_bits(v - hf);
        (sel ? h2 : h1)[idx] = (unsigned short)hb;
        (sel ? l2 : l1)[idx] = (unsigned short)l;
    } else if (b < ncast + 512) {
        // coarse histogram (bucket = dst>>8), per-block row in chist2
        const int cb = b - ncast - 256;
        h[t] = 0;
        __syncthreads();
        for (int e = cb * 256 + t; e < E; e += 65536)
            atomicAdd(&h[dst[e] >> 8], 1);
        __syncthreads();
        chist2[cb * 256 + t] = h[t];
    } else {
        if (t < 32) csrpad[t] = 0;
    }
}

// ---------------- pass B: reduce chist2 + scan -> cbase (excl, 257) + gcur ----------------
__global__ __launch_bounds__(256) void scan256_kernel(const int* __restrict__ chist2,
                                                      int* __restrict__ cbase,
                                                      int* __restrict__ gcur) {
    __shared__ int wsum[4];
    const int t = threadIdx.x, lane = t & 63, wv = t >> 6;
    int v = 0;
#pragma unroll 8
    for (int b = 0; b < 256; ++b) v += chist2[b * 256 + t];   // coalesced per row
    int s = v;
#pragma unroll
    for (int o = 1; o < 64; o <<= 1) {
        int u = __shfl_up(s, o, 64);
        if (lane >= o) s += u;
    }
    if (lane == 63) wsum[wv] = s;
    __syncthreads();
    int add = 0;
    for (int w = 0; w < wv; ++w) add += wsum[w];
    cbase[t + 1] = s + add;
    if (t == 0) cbase[0] = 0;
    gcur[t] = s + add - v;
}

// ---------------- pass C: coarse multisplit scatter ----------------
#define CCHUNK 4096
__global__ __launch_bounds__(256) void coarse_scatter_kernel(
    const int* __restrict__ src, const int* __restrict__ dst,
    int* __restrict__ gcur, unsigned int* __restrict__ centries, int E)
{
    __shared__ int h[256];
    __shared__ int base[256];
    __shared__ unsigned int stage[CCHUNK];
    const int t = threadIdx.x;
    const int e0 = blockIdx.x * CCHUNK;
    h[t] = 0;
    __syncthreads();
#pragma unroll
    for (int i = 0; i < 16; ++i) {
        int e = e0 + i * 256 + t;
        unsigned int u = 0xFFFFFFFFu;
        if (e < E) {
            int d = dst[e];
            int s = src[e];
            int b = d >> 8;
            u = ((unsigned)b << 24) | ((unsigned)s << 8) | (unsigned)(d & 255);
            atomicAdd(&h[b], 1);
        }
        stage[i * 256 + t] = u;
    }
    __syncthreads();
    base[t] = atomicAdd(&gcur[t], h[t]);
    __syncthreads();
    h[t] = 0;
    __syncthreads();
#pragma unroll
    for (int i = 0; i < 16; ++i) {
        unsigned int u = stage[i * 256 + t];
        if (u != 0xFFFFFFFFu) {
            int b = u >> 24;
            int r = atomicAdd(&h[b], 1);
            centries[base[b] + r] = u & 0x00FFFFFFu;
        }
    }
}

// ---------------- pass D: fine bucket (one block per coarse bucket) ----------------
#define DCAP 8192
__global__ __launch_bounds__(256) void fine_bucket_kernel(
    const unsigned int* __restrict__ centries,
    const int* __restrict__ cbase,
    int* __restrict__ offo, int* __restrict__ csr, int N, int E)
{
    __shared__ int h[256], ex[256], wsum[4];
    __shared__ int stg[DCAP];
    const int t = threadIdx.x, lane = t & 63, wv = t >> 6;
    const int b = blockIdx.x;
    const int s0 = cbase[b];
    const int cnt = cbase[b + 1] - s0;
    h[t] = 0;
    __syncthreads();
    for (int i = t; i < cnt; i += 256)
        atomicAdd(&h[centries[s0 + i] & 255], 1);
    __syncthreads();
    int v = h[t], s = v;
#pragma unroll
    for (int o = 1; o < 64; o <<= 1) {
        int u = __shfl_up(s, o, 64);
        if (lane >= o) s += u;
    }
    if (lane == 63) wsum[wv] = s;
    __syncthreads();
    int add = 0;
    for (int w = 0; w < wv; ++w) add += wsum[w];
    const int exc = s + add - v;
    ex[t] = exc;
    const int dg = b * 256 + t;
    if (dg < N) offo[dg] = s0 + exc;
    if (b == 0 && t == 0) offo[N] = E;
    h[t] = 0;
    __syncthreads();
    if (cnt <= DCAP) {
        for (int i = t; i < cnt; i += 256) {
            unsigned int u = centries[s0 + i];
            int dl = u & 255;
            int r = atomicAdd(&h[dl], 1);
            stg[ex[dl] + r] = (int)(u >> 8);
        }
        __syncthreads();
        for (int i = t; i < cnt; i += 256)
            csr[s0 + i] = stg[i];
    } else {
        for (int i = t; i < cnt; i += 256) {
            unsigned int u = centries[s0 + i];
            int dl = u & 255;
            int r = atomicAdd(&h[dl], 1);
            csr[s0 + ex[dl] + r] = (int)(u >> 8);
        }
    }
}

// ---------------- fused gather-mean + MFMA GEMM (4 waves per tile) ----------------
// R5 structure (best measured: 55.9us, FETCH 96MB, occ 60%) + 256B-ALIGNED
// feature tables (r11 lesson: tables at mod-256=64 made every 256B row span
// 3x128B lines instead of 2 -> FETCH 96->133MB, +6us/dispatch).
__global__ __launch_bounds__(256, 4) void fused_sage_kernel(
    const unsigned short* __restrict__ featbf,    // gather table (bf16 hi), row-major
    const int* __restrict__ off,
    const int* __restrict__ csr,
    const unsigned short* __restrict__ self_hi,   // row-major bf16 (hi)
    const unsigned short* __restrict__ self_lo,   // row-major bf16 (lo)
    const unsigned short* __restrict__ wpk_hi,
    const unsigned short* __restrict__ wpk_lo,
    const float* __restrict__ bias,
    unsigned short* __restrict__ out_hi,          // row-major bf16
    unsigned short* __restrict__ out_lo,          // nullable (layer-1 h lo)
    int do_relu)
{
    __shared__ unsigned short AHs[4][64][8];      // [ks][mfma-lane][j]
    __shared__ unsigned short ALs[4][64][8];
    __shared__ unsigned short outs_hi[16][128];
    __shared__ unsigned short outs_lo[16][128];

    const int w = threadIdx.x >> 6;               // wave 0..3
    const int l = threadIdx.x & 63;
    const int tile = blockIdx.x;
    const int n0w = tile * 16;

    // ---- gather phase ----
    const int gn = l >> 2;                        // node 0..15
    const int q2 = l & 3;                         // channel sub-block
    const int gnode = n0w + gn;
    const int start = off[gnode];
    const int end   = off[gnode + 1];
    const unsigned short* fb = featbf + w * 32 + q2 * 8;

    float ga[8] = {0.f, 0.f, 0.f, 0.f, 0.f, 0.f, 0.f, 0.f};

#define ACC(rv)                                                         \
    { ga[0] += bfhi(rv.x); ga[1] += bflo(rv.x);                         \
      ga[2] += bfhi(rv.y); ga[3] += bflo(rv.y);                         \
      ga[4] += bfhi(rv.z); ga[5] += bflo(rv.z);                         \
      ga[6] += bfhi(rv.w); ga[7] += bflo(rv.w); }

    const uint4 zero4 = {0u, 0u, 0u, 0u};
    if (start < end) {
        int4 ix = *(const int4*)(csr + start);
        uint4 c0 = *(const uint4*)(fb + (size_t)ix.x * D);
        uint4 c1 = *(const uint4*)(fb + (size_t)ix.y * D);
        uint4 c2 = *(const uint4*)(fb + (size_t)ix.z * D);
        uint4 c3 = *(const uint4*)(fb + (size_t)ix.w * D);
        for (int e = start; e < end; e += 4) {
            // depth-2: issue next batch (pad-safe overshoot) before accumulating
            int4 ixn = *(const int4*)(csr + e + 4);
            uint4 n0 = *(const uint4*)(fb + (size_t)ixn.x * D);
            uint4 n1 = *(const uint4*)(fb + (size_t)ixn.y * D);
            uint4 n2 = *(const uint4*)(fb + (size_t)ixn.z * D);
            uint4 n3 = *(const uint4*)(fb + (size_t)ixn.w * D);
            if (e + 1 >= end) c1 = zero4;
            if (e + 2 >= end) c2 = zero4;
            if (e + 3 >= end) c3 = zero4;
            ACC(c0) ACC(c1) ACC(c2) ACC(c3)
            c0 = n0; c1 = n1; c2 = n2; c3 = n3;
        }
    }
#undef ACC

    // mean + bf16 hi/lo split -> LDS frag exchange
    {
        const float dinv = 1.0f / (float)max(end - start, 1);
        short8 hi8, lo8;
#pragma unroll
        for (int c = 0; c < 8; ++c) {
            float v = ga[c] * dinv;
            unsigned int hb = f2bf_bits(v);
            hi8[c] = (short)hb;
            lo8[c] = (short)f2bf_bits(v - __uint_as_float(hb << 16));
        }
        // MFMA lane (q=q2, r16=gn) consumes this as frag ks=w
        *(short8*)&AHs[w][q2 * 16 + gn][0] = hi8;
        *(short8*)&ALs[w][q2 * 16 + gn][0] = lo8;
    }
    __syncthreads();

    // ---- MFMA phase: wave w computes t = 2w, 2w+1 ----
    const int q = l >> 4, r16 = l & 15;
    const int mnode = n0w + r16;
    f32x4 acc0 = {0.f, 0.f, 0.f, 0.f};
    f32x4 acc1 = {0.f, 0.f, 0.f, 0.f};
    const unsigned short* sph = self_hi + (size_t)mnode * D + q * 8;
    const unsigned short* spl = self_lo + (size_t)mnode * D + q * 8;
    const unsigned short* bh0 = wpk_hi + (size_t)(2 * w) * 4096 + l * 8;
    const unsigned short* bl0 = wpk_lo + (size_t)(2 * w) * 4096 + l * 8;

#pragma unroll
    for (int ks = 0; ks < 8; ++ks) {
        short8 AH, AL;
        if (ks < 4) {
            AH = *(const short8*)&AHs[ks][l][0];
            AL = *(const short8*)&ALs[ks][l][0];
        } else {
            AH = *(const short8*)(sph + (ks - 4) * 32);
            AL = *(const short8*)(spl + (ks - 4) * 32);
        }
        short8 BH0 = *(const short8*)(bh0 + ks * 512);
        short8 BL0 = *(const short8*)(bl0 + ks * 512);
        short8 BH1 = *(const short8*)(bh0 + 4096 + ks * 512);
        short8 BL1 = *(const short8*)(bl0 + 4096 + ks * 512);
        acc0 = __builtin_amdgcn_mfma_f32_16x16x32_bf16(AH, BH0, acc0, 0, 0, 0);
        acc0 = __builtin_amdgcn_mfma_f32_16x16x32_bf16(AL, BH0, acc0, 0, 0, 0);
        acc0 = __builtin_amdgcn_mfma_f32_16x16x32_bf16(AH, BL0, acc0, 0, 0, 0);
        acc1 = __builtin_amdgcn_mfma_f32_16x16x32_bf16(AH, BH1, acc1, 0, 0, 0);
        acc1 = __builtin_amdgcn_mfma_f32_16x16x32_bf16(AL, BH1, acc1, 0, 0, 0);
        acc1 = __builtin_amdgcn_mfma_f32_16x16x32_bf16(AH, BL1, acc1, 0, 0, 0);
    }

    // ---- epilogue: bias/relu/split -> LDS tile -> coalesced stream ----
    {
        const float bv0 = bias[32 * w + r16];
        const float bv1 = bias[32 * w + 16 + r16];
#pragma unroll
        for (int r = 0; r < 4; ++r) {
            float v0 = acc0[r] + bv0;
            float v1 = acc1[r] + bv1;
            if (do_relu) { v0 = fmaxf(v0, 0.f); v1 = fmaxf(v1, 0.f); }
            const int row = q * 4 + r;
            unsigned int h0 = f2bf_bits(v0);
            unsigned int h1 = f2bf_bits(v1);
            outs_hi[row][32 * w + r16] = (unsigned short)h0;
            outs_hi[row][32 * w + 16 + r16] = (unsigned short)h1;
            outs_lo[row][32 * w + r16] =
                (unsigned short)f2bf_bits(v0 - __uint_as_float(h0 << 16));
            outs_lo[row][32 * w + 16 + r16] =
                (unsigned short)f2bf_bits(v1 - __uint_as_float(h1 << 16));
        }
    }
    __syncthreads();
    {
        const int tid = threadIdx.x;
        short8 vh = *(short8*)(&outs_hi[0][0] + tid * 8);
        *(short8*)(out_hi + (size_t)n0w * D + tid * 8) = vh;
        if (out_lo) {
            short8 vl = *(short8*)(&outs_lo[0][0] + tid * 8);
            *(short8*)(out_lo + (size_t)n0w * D + tid * 8) = vl;
        }
    }
}

// ---------------- edge dot-product decode (bf16 z rows) ----------------
// 16 lanes per edge, 16 B loads, reduce depth 4.
__global__ __launch_bounds__(256) void pred_kernel(const unsigned short* __restrict__ zbf,
                                                   const int* __restrict__ ps,
                                                   const int* __restrict__ pd,
                                                   float* __restrict__ out, int EP) {
    int idx = blockIdx.x * 256 + threadIdx.x;
    int e = idx >> 4;
    if (e >= EP) return;
    int L = idx & 15;
    const unsigned short* fb = zbf + (size_t)L * 8;
    uint4 ra = *(const uint4*)(fb + (size_t)ps[e] * D);
    uint4 rb = *(const uint4*)(fb + (size_t)pd[e] * D);
    float p = bfhi(ra.x) * bfhi(rb.x) + bflo(ra.x) * bflo(rb.x)
            + bfhi(ra.y) * bfhi(rb.y) + bflo(ra.y) * bflo(rb.y)
            + bfhi(ra.z) * bfhi(rb.z) + bflo(ra.z) * bflo(rb.z)
            + bfhi(ra.w) * bfhi(rb.w) + bflo(ra.w) * bflo(rb.w);
#pragma unroll
    for (int off = 8; off > 0; off >>= 1) p += __shfl_xor(p, off, 16);
    if (L == 0) out[e] = p;
}

extern "C" void kernel_launch(void* const* d_in, const int* in_sizes, int n_in,
                              void* d_out, int out_size, void* d_ws, size_t ws_size,
                              hipStream_t stream) {
    const float* x   = (const float*)d_in[0];
    const float* W1l = (const float*)d_in[1];
    const float* b1  = (const float*)d_in[2];
    const float* W1r = (const float*)d_in[3];
    const float* W2l = (const float*)d_in[4];
    const float* b2  = (const float*)d_in[5];
    const float* W2r = (const float*)d_in[6];
    const int* edge_index = (const int*)d_in[7];
    const int* pred_edges = (const int*)d_in[8];
    float* out = (float*)d_out;

    const int N  = in_sizes[0] / D;   // 50000
    const int E  = in_sizes[7] / 2;   // 800000
    const int EP = in_sizes[8] / 2;   // 200000

    const int* src = edge_index;
    const int* dst = edge_index + E;
    const int* ps  = pred_edges;
    const int* pd  = pred_edges + EP;

    // workspace layout (feature tables 256B-aligned: +48 int pad after csr)
    int* chist2  = (int*)d_ws;                 // 65536 (256KB, aligned)
    int* cbase   = chist2 + 65536;             // 257 (pad 272)
    int* gcur    = cbase + 272;                // 256
    int* off     = gcur + 256;                 // N+1 (pad 50016)
    unsigned int* centries = (unsigned int*)(off + 50016);  // E
    int* csr     = (int*)(centries + E);       // E + 32 pad
    // ints so far: 65536+272+256+50016+E+E+32 = 1,716,112 -> pad +48 -> 1,716,160
    // (x4 = 6,864,640 bytes, 256B-aligned; all following buffers are 256B multiples)
    unsigned short* w1_hi = (unsigned short*)(csr + E + 32 + 48);
    unsigned short* w1_lo = w1_hi + 32768;
    unsigned short* w2_hi = w1_lo + 32768;
    unsigned short* w2_lo = w2_hi + 32768;
    unsigned short* xbf   = w2_lo + 32768;          // N*D bf16 (x hi), 256B-aligned
    unsigned short* xlo   = xbf + (size_t)N * D;    // N*D bf16 (x lo)
    unsigned short* hbf   = xlo + (size_t)N * D;    // N*D bf16 (h hi)
    unsigned short* hlo   = hbf + (size_t)N * D;    // N*D bf16 (h lo)
    unsigned short* zbf   = hlo + (size_t)N * D;    // N*D bf16 (z)

    const int n4 = N * D / 4;
    const int ncast = (n4 + 255) / 256;             // 6250
    const int ntiles = N / 16;                      // 3125
    const int nbC = (E + CCHUNK - 1) / CCHUNK;      // 196
    const int nbD = (N + 255) / 256;                // 196
    const int nblk_pred = (EP * 16 + 255) / 256;    // 12500

    // fused prep: x hi/lo cast + weight pack + coarse count + csr pad zero
    prep_kernel<<<ncast + 513, 256, 0, stream>>>(x, W1l, W1r, W2l, W2r, dst, E,
                                                 xbf, xlo, w1_hi, w1_lo, w2_hi, w2_lo,
                                                 n4, ncast, chist2, csr + E);

    // CSR build: scan (reduces chist2) -> coarse multisplit -> fine bucket
    scan256_kernel<<<1, 256, 0, stream>>>(chist2, cbase, gcur);
    coarse_scatter_kernel<<<nbC, 256, 0, stream>>>(src, dst, gcur, centries, E);
    fine_bucket_kernel<<<nbD, 256, 0, stream>>>(centries, cbase, off, csr, N, E);

    // layer 1: h = relu(mean(x)@W1l + x@W1r + b1) -> hbf/hlo
    fused_sage_kernel<<<ntiles, 256, 0, stream>>>(xbf, off, csr, xbf, xlo,
                                                  w1_hi, w1_lo, b1, hbf, hlo, 1);
    // layer 2: z = mean(h)@W2l + h@W2r + b2 -> zbf
    fused_sage_kernel<<<ntiles, 256, 0, stream>>>(hbf, off, csr, hbf, hlo,
                                                  w2_hi, w2_lo, b2, zbf,
                                                  (unsigned short*)nullptr, 0);
    // decode from bf16 z
    pred_kernel<<<nblk_pred, 256, 0, stream>>>(zbf, ps, pd, out, EP);
}